// Round 10
// baseline (35.208 us; speedup 1.0000x reference)
//
#include <hip/hip_runtime.h>

// 5x5 median, replicate borders, C=3, H=W=2048, fp32.
// Single fused kernel, branch-free, packed-bf16 (error <= 2^-9 << 1.88e-2).
// 4 px/thread, pairs (x, x+2) in u32 lanes; network on v_pk_min/max_u16.
//   raw[j] = col x0-2+j (j=0..7, x-replicate-clamped)
//   P[j] = pack(bf16(raw[j]) lo, bf16(raw[j+2]) hi), j = 0..5
//   windows: px x0 = lo P[0..4], px x0+1 = lo P[1..5],
//            px x0+2 = hi P[0..4], px x0+3 = hi P[1..5]
//   6x sort5 + merge55(P1,P2), merge55(P3,P4) + ONE shared mid6
//   + rank5(V, P[0]) and rank5(V, P[5]).

typedef unsigned int u32;

__device__ __forceinline__ u32 pmn(u32 a, u32 b) {
    u32 r;
    asm("v_pk_min_u16 %0, %1, %2" : "=v"(r) : "v"(a), "v"(b));
    return r;
}
__device__ __forceinline__ u32 pmx(u32 a, u32 b) {
    u32 r;
    asm("v_pk_max_u16 %0, %1, %2" : "=v"(r) : "v"(a), "v"(b));
    return r;
}

#define PCE(i, j)                     \
    {                                 \
        u32 a_ = v[i], b_ = v[j];     \
        v[i] = pmn(a_, b_);           \
        v[j] = pmx(a_, b_);           \
    }

// Knuth's optimal 9-CE sorting network for 5 (packed).
__device__ __forceinline__ void sort5p(u32 (&v)[5]) {
    PCE(0, 1) PCE(3, 4) PCE(2, 4) PCE(2, 3) PCE(0, 3) PCE(0, 2) PCE(1, 4) PCE(1, 3) PCE(1, 2)
}

// Batcher odd-even merge of two sorted 5-arrays -> sorted 10 (packed). 13 CEs.
__device__ __forceinline__ void merge55p(const u32 (&A)[5], const u32 (&B)[5], u32 (&C)[10]) {
    u32 re0 = pmn(A[0], B[0]), re1 = pmx(A[0], B[0]);
    u32 ro0 = pmn(A[4], B[4]), ro1 = pmx(A[4], B[4]);
    u32 R1 = pmn(re1, ro0), R2 = pmx(re1, ro0);
    u32 s0 = pmn(A[2], B[2]), s1 = pmx(A[2], B[2]);
    u32 P1 = pmn(R1, s0), P2 = pmx(R1, s0);
    u32 P3 = pmn(R2, s1), P4 = pmx(R2, s1);
    u32 qe0 = pmn(A[1], B[1]), qe1 = pmx(A[1], B[1]);
    u32 qo0 = pmn(A[3], B[3]), qo1 = pmx(A[3], B[3]);
    u32 Q1 = pmn(qe1, qo0), Q2 = pmx(qe1, qo0);
    C[0] = re0;
    C[1] = pmn(P1, qe0); C[2] = pmx(P1, qe0);
    C[3] = pmn(P2, Q1);  C[4] = pmx(P2, Q1);
    C[5] = pmn(P3, Q2);  C[6] = pmx(P3, Q2);
    C[7] = pmn(P4, qo1); C[8] = pmx(P4, qo1);
    C[9] = ro1;
}

// Middle six (ranks 7..12, sorted) of merge(S10,T10): pruned Batcher merge.
__device__ __forceinline__ void mid6p(const u32 (&S)[10], const u32 (&T)[10], u32 (&V)[6]) {
    u32 e1 = pmx(S[0], T[0]);
    u32 o0 = pmn(S[8], T[8]);
    u32 R1 = pmn(e1, o0), R2 = pmx(e1, o0);
    u32 s0 = pmn(S[4], T[4]), s1 = pmx(S[4], T[4]);
    u32 qe1 = pmx(S[2], T[2]), qo0 = pmn(S[6], T[6]);
    u32 Q1 = pmn(qe1, qo0), Q2 = pmx(qe1, qo0);
    u32 E4 = pmx(pmx(R1, s0), Q1);
    u32 P3 = pmn(R2, s1);
    u32 E5 = pmn(P3, Q2), E6 = pmx(P3, Q2);
    u32 f1 = pmx(S[1], T[1]);
    u32 g0 = pmn(S[9], T[9]);
    u32 R1o = pmn(f1, g0), R2o = pmx(f1, g0);
    u32 t0 = pmn(S[5], T[5]), t1 = pmx(S[5], T[5]);
    u32 qf1 = pmx(S[3], T[3]), qg0 = pmn(S[7], T[7]);
    u32 Q1o = pmn(qf1, qg0), Q2o = pmx(qf1, qg0);
    u32 P2o = pmx(R1o, t0);
    u32 O3 = pmn(P2o, Q1o), O4 = pmx(P2o, Q1o);
    u32 O5 = pmn(pmn(R2o, t1), Q2o);
    V[0] = pmn(E4, O3); V[1] = pmx(E4, O3);
    V[2] = pmn(E5, O4); V[3] = pmx(E5, O4);
    V[4] = pmn(E6, O5); V[5] = pmx(E6, O5);
}

// rank-5 of V(6 sorted) u G(5 sorted): max over splits of min(V[i],G[j]).
__device__ __forceinline__ u32 rank5p(const u32 (&V)[6], const u32 (&G)[5]) {
    u32 m1 = pmn(V[1], G[4]);
    u32 m2 = pmn(V[2], G[3]);
    u32 m3 = pmn(V[3], G[2]);
    u32 m4 = pmn(V[4], G[1]);
    u32 m5 = pmn(V[5], G[0]);
    return pmx(pmx(pmx(V[0], m1), m2), pmx(pmx(m3, m4), m5));
}

__global__ __launch_bounds__(256) void median5x5_all(const u32* __restrict__ in,
                                                     u32* __restrict__ out) {
    const int W = 2048, H = 2048;
    const int q = blockIdx.x * 64 + threadIdx.x;  // 0..511; pixels 4q..4q+3
    const int y = blockIdx.y * 4 + threadIdx.y;
    const size_t plane = (size_t)blockIdx.z * (size_t)(H * W);
    const u32* __restrict__ src = in + plane;

    const int x0 = 4 * q;
    const int colE = (x0 - 2) < 0 ? 0 : (x0 - 2);        // raw[0,1]
    const int colG = (x0 + 4) > 2046 ? 2046 : (x0 + 4);  // raw[6,7]
    const bool q0 = (q == 0);
    const bool q511 = (q == 511);

    // raw[j] = col x0-2+j, j = 0..7 (x-replicate-clamped).
    // Unconditional loads: E(uint2)@colE, F(uint4)@x0, G(uint2)@colG.
    // Fixups (verified case-by-case):
    //   raw[1] = q0 ? E.x : E.y      (col -1 -> 0 at left border)
    //   raw[6] = q511 ? G.y : G.x    (col 2048 -> 2047 at right border)
    //   raw[7] = G.y                 (normal: col x0+5; q511: 2047 replicate)
    // P[j] = pack(bf16(raw[j]) lo, bf16(raw[j+2]) hi); perm sel 0x07060302
    // takes the high 16 bits of each f32 (= bf16 truncation).
    u32 P[6][5];
#pragma unroll
    for (int r = 0; r < 5; ++r) {
        int yy = y - 2 + r;
        yy = yy < 0 ? 0 : (yy > H - 1 ? H - 1 : yy);
        const u32* rowp = src + (size_t)yy * W;
        uint2 e = *(const uint2*)(rowp + colE);
        uint4 f = *(const uint4*)(rowp + x0);
        uint2 gg = *(const uint2*)(rowp + colG);
        u32 raw[8];
        raw[0] = e.x;
        raw[1] = q0 ? e.x : e.y;
        raw[2] = f.x; raw[3] = f.y; raw[4] = f.z; raw[5] = f.w;
        raw[6] = q511 ? gg.y : gg.x;
        raw[7] = gg.y;
#pragma unroll
        for (int j = 0; j < 6; ++j)
            P[j][r] = __builtin_amdgcn_perm(raw[j + 2], raw[j], 0x07060302u);
    }

#pragma unroll
    for (int j = 0; j < 6; ++j) sort5p(P[j]);

    u32 M12[10], M34[10];
    merge55p(P[1], P[2], M12);
    merge55p(P[3], P[4], M34);

    u32 V[6];
    mid6p(M12, M34, V);  // shared by all four windows

    u32 o0 = rank5p(V, P[0]);  // lo: median(x0),   hi: median(x0+2)
    u32 o1 = rank5p(V, P[5]);  // lo: median(x0+1), hi: median(x0+3)

    // out[x0..x0+3] = {o0.lo, o1.lo, o0.hi, o1.hi} as f32 (bf16 << 16)
    uint4 o;
    o.x = o0 << 16;
    o.y = o1 << 16;
    o.z = o0 & 0xffff0000u;
    o.w = o1 & 0xffff0000u;
    *(uint4*)(out + plane + (size_t)y * W + x0) = o;
}

extern "C" void kernel_launch(void* const* d_in, const int* in_sizes, int n_in,
                              void* d_out, int out_size, void* d_ws, size_t ws_size,
                              hipStream_t stream) {
    const u32* in = (const u32*)d_in[0];
    u32* out = (u32*)d_out;
    dim3 block(64, 4, 1);
    dim3 grid(8, 512, 3);
    hipLaunchKernelGGL(median5x5_all, grid, block, 0, stream, in, out);
}

// Round 11
// 32.787 us; speedup vs baseline: 1.0738x; 1.0738x over previous
//
#include <hip/hip_runtime.h>

// 5x5 median, replicate borders, C=3, H=W=2048, fp32.
// Single fused kernel, branch-free, packed-bf16 (error <= 2^-9 << 1.88e-2).
// R11: R7's 8px/thread packed network + 4-row software-pipelined y-loop.
// Each thread: pixels x=8g..8g+7, rows y = 16*by + ty + 4i, i=0..3.
// Loop: pack(iter i) -> issue loads(iter i+1) -> network+store(iter i).
// Loads for i+1 are in flight during iter i's ~500-cyc network, so wave
// phases decorrelate (fixes the phase-synchronized stall that capped
// VALUBusy at 38%).

typedef unsigned int u32;

__device__ __forceinline__ u32 pmn(u32 a, u32 b) {
    u32 r;
    asm("v_pk_min_u16 %0, %1, %2" : "=v"(r) : "v"(a), "v"(b));
    return r;
}
__device__ __forceinline__ u32 pmx(u32 a, u32 b) {
    u32 r;
    asm("v_pk_max_u16 %0, %1, %2" : "=v"(r) : "v"(a), "v"(b));
    return r;
}

#define PCE(i, j)                     \
    {                                 \
        u32 a_ = v[i], b_ = v[j];     \
        v[i] = pmn(a_, b_);           \
        v[j] = pmx(a_, b_);           \
    }

// Knuth's optimal 9-CE sorting network for 5 (packed).
__device__ __forceinline__ void sort5p(u32 (&v)[5]) {
    PCE(0, 1) PCE(3, 4) PCE(2, 4) PCE(2, 3) PCE(0, 3) PCE(0, 2) PCE(1, 4) PCE(1, 3) PCE(1, 2)
}

// Batcher odd-even merge of two sorted 5-arrays -> sorted 10 (packed). 13 CEs.
__device__ __forceinline__ void merge55p(const u32 (&A)[5], const u32 (&B)[5], u32 (&C)[10]) {
    u32 re0 = pmn(A[0], B[0]), re1 = pmx(A[0], B[0]);
    u32 ro0 = pmn(A[4], B[4]), ro1 = pmx(A[4], B[4]);
    u32 R1 = pmn(re1, ro0), R2 = pmx(re1, ro0);
    u32 s0 = pmn(A[2], B[2]), s1 = pmx(A[2], B[2]);
    u32 P1 = pmn(R1, s0), P2 = pmx(R1, s0);
    u32 P3 = pmn(R2, s1), P4 = pmx(R2, s1);
    u32 qe0 = pmn(A[1], B[1]), qe1 = pmx(A[1], B[1]);
    u32 qo0 = pmn(A[3], B[3]), qo1 = pmx(A[3], B[3]);
    u32 Q1 = pmn(qe1, qo0), Q2 = pmx(qe1, qo0);
    C[0] = re0;
    C[1] = pmn(P1, qe0); C[2] = pmx(P1, qe0);
    C[3] = pmn(P2, Q1);  C[4] = pmx(P2, Q1);
    C[5] = pmn(P3, Q2);  C[6] = pmx(P3, Q2);
    C[7] = pmn(P4, qo1); C[8] = pmx(P4, qo1);
    C[9] = ro1;
}

// Middle six (ranks 7..12, sorted) of merge(S10,T10): pruned Batcher merge.
__device__ __forceinline__ void mid6p(const u32 (&S)[10], const u32 (&T)[10], u32 (&V)[6]) {
    u32 e1 = pmx(S[0], T[0]);
    u32 o0 = pmn(S[8], T[8]);
    u32 R1 = pmn(e1, o0), R2 = pmx(e1, o0);
    u32 s0 = pmn(S[4], T[4]), s1 = pmx(S[4], T[4]);
    u32 qe1 = pmx(S[2], T[2]), qo0 = pmn(S[6], T[6]);
    u32 Q1 = pmn(qe1, qo0), Q2 = pmx(qe1, qo0);
    u32 E4 = pmx(pmx(R1, s0), Q1);
    u32 P3 = pmn(R2, s1);
    u32 E5 = pmn(P3, Q2), E6 = pmx(P3, Q2);
    u32 f1 = pmx(S[1], T[1]);
    u32 g0 = pmn(S[9], T[9]);
    u32 R1o = pmn(f1, g0), R2o = pmx(f1, g0);
    u32 t0 = pmn(S[5], T[5]), t1 = pmx(S[5], T[5]);
    u32 qf1 = pmx(S[3], T[3]), qg0 = pmn(S[7], T[7]);
    u32 Q1o = pmn(qf1, qg0), Q2o = pmx(qf1, qg0);
    u32 P2o = pmx(R1o, t0);
    u32 O3 = pmn(P2o, Q1o), O4 = pmx(P2o, Q1o);
    u32 O5 = pmn(pmn(R2o, t1), Q2o);
    V[0] = pmn(E4, O3); V[1] = pmx(E4, O3);
    V[2] = pmn(E5, O4); V[3] = pmx(E5, O4);
    V[4] = pmn(E6, O5); V[5] = pmx(E6, O5);
}

// rank-5 of V(6 sorted) u G(5 sorted): max over splits of min(V[i],G[j]).
__device__ __forceinline__ u32 rank5p(const u32 (&V)[6], const u32 (&G)[5]) {
    u32 m1 = pmn(V[1], G[4]);
    u32 m2 = pmn(V[2], G[3]);
    u32 m3 = pmn(V[3], G[2]);
    u32 m4 = pmn(V[4], G[1]);
    u32 m5 = pmn(V[5], G[0]);
    return pmx(pmx(pmx(V[0], m1), m2), pmx(pmx(m3, m4), m5));
}

__global__ __launch_bounds__(256) void median5x5_all(const u32* __restrict__ in,
                                                     u32* __restrict__ out) {
    const int W = 2048, H = 2048;
    const int g = blockIdx.x * 64 + threadIdx.x;  // 0..255; pixels 8g..8g+7
    const int ybase = blockIdx.y * 16 + threadIdx.y;  // rows ybase + 4i
    const size_t plane = (size_t)blockIdx.z * (size_t)(H * W);
    const u32* __restrict__ src = in + plane;

    const int base = 8 * g;
    const int colA = (base - 2) < 0 ? 0 : (base - 2);        // raw[0,1]
    const int colD = (base + 8) > 2046 ? 2046 : (base + 8);  // raw[10,11]
    const bool g0 = (g == 0);
    const bool g255 = (g == 255);

    uint2 A[5], D[5];
    uint4 B[5], C[5];

    // prologue: loads for iteration 0
#pragma unroll
    for (int r = 0; r < 5; ++r) {
        int yy = ybase - 2 + r;
        yy = yy < 0 ? 0 : (yy > H - 1 ? H - 1 : yy);
        const u32* rowp = src + (size_t)yy * W;
        A[r] = *(const uint2*)(rowp + colA);
        B[r] = *(const uint4*)(rowp + base);
        C[r] = *(const uint4*)(rowp + base + 4);
        D[r] = *(const uint2*)(rowp + colD);
    }

#pragma unroll
    for (int i = 0; i < 4; ++i) {
        const int y = ybase + 4 * i;

        // ---- pack current rows into bf16x2 columns (consumes A/B/C/D) ----
        // raw[j] = col base-2+j; fixups: raw[1] = g0 ? A.x : A.y,
        // raw[10] = g255 ? D.y : D.x; raw[0]=A.x, raw[11]=D.y always correct.
        // perm sel 0x07060302 = high 16 bits of each f32 = bf16 truncation.
        u32 P[8][5];
#pragma unroll
        for (int r = 0; r < 5; ++r) {
            u32 raw[12];
            raw[0] = A[r].x;
            raw[1] = g0 ? A[r].x : A[r].y;
            raw[2] = B[r].x;  raw[3] = B[r].y;  raw[4] = B[r].z;  raw[5] = B[r].w;
            raw[6] = C[r].x;  raw[7] = C[r].y;  raw[8] = C[r].z;  raw[9] = C[r].w;
            raw[10] = g255 ? D[r].y : D[r].x;
            raw[11] = D[r].y;
#pragma unroll
            for (int j = 0; j < 8; ++j)
                P[j][r] = __builtin_amdgcn_perm(raw[j + 4], raw[j], 0x07060302u);
        }

        // ---- issue next iteration's loads (fly during the network) ----
        if (i < 3) {
            const int yn = y + 4;
#pragma unroll
            for (int r = 0; r < 5; ++r) {
                int yy = yn - 2 + r;
                yy = yy < 0 ? 0 : (yy > H - 1 ? H - 1 : yy);
                const u32* rowp = src + (size_t)yy * W;
                A[r] = *(const uint2*)(rowp + colA);
                B[r] = *(const uint4*)(rowp + base);
                C[r] = *(const uint4*)(rowp + base + 4);
                D[r] = *(const uint2*)(rowp + colD);
            }
        }

        // ---- packed selection network ----
#pragma unroll
        for (int j = 0; j < 8; ++j) sort5p(P[j]);

        u32 M12[10], M34[10], M56[10];
        merge55p(P[1], P[2], M12);
        merge55p(P[3], P[4], M34);
        merge55p(P[5], P[6], M56);

        u32 VA[6], VB[6];
        mid6p(M12, M34, VA);  // windows P[0..4] and P[1..5]
        mid6p(M34, M56, VB);  // windows P[2..6] and P[3..7]

        u32 o0 = rank5p(VA, P[0]);
        u32 o1 = rank5p(VA, P[5]);
        u32 o2 = rank5p(VB, P[2]);
        u32 o3 = rank5p(VB, P[7]);

        // lo half -> pixel 8g+i, hi half -> pixel 8g+4+i
        u32* op = out + plane + (size_t)y * W + base;
        uint4 e, o;
        e.x = o0 << 16; e.y = o1 << 16; e.z = o2 << 16; e.w = o3 << 16;
        o.x = o0 & 0xffff0000u; o.y = o1 & 0xffff0000u;
        o.z = o2 & 0xffff0000u; o.w = o3 & 0xffff0000u;
        *(uint4*)(op) = e;
        *(uint4*)(op + 4) = o;
    }
}

extern "C" void kernel_launch(void* const* d_in, const int* in_sizes, int n_in,
                              void* d_out, int out_size, void* d_ws, size_t ws_size,
                              hipStream_t stream) {
    const u32* in = (const u32*)d_in[0];
    u32* out = (u32*)d_out;
    dim3 block(64, 4, 1);
    dim3 grid(4, 128, 3);
    hipLaunchKernelGGL(median5x5_all, grid, block, 0, stream, in, out);
}